// Round 6
// baseline (555.204 us; speedup 1.0000x reference)
//
#include <hip/hip_runtime.h>
#include <hip/hip_bf16.h>

// Problem constants
#define NNEUR 8192
#define NCONV 64
#define LYC   36
#define LXC   36
#define BATCH 256
#define KRAW  1296   // 36*36
#define KPAD  1344   // 21*64
#define KITER 21     // KPAD/64
#define MROWS 16384  // BATCH*NCONV
#define BM 128
#define BN 128
#define BK 64
// One (tile, it) image = BM*BK = 8192 halfs = 1024 chunks of 16B = 16 KB.
#define IT_H     8192                  // halfs per (tile, it)
#define TILE_H   (KITER * IT_H)        // 172032 halfs per tile (A and B)

typedef __attribute__((ext_vector_type(8))) _Float16 half8;
typedef __attribute__((ext_vector_type(4))) float f32x4;
typedef __attribute__((ext_vector_type(16))) float f32x16;

__device__ __forceinline__ void async_copy16(const void* g, void* l) {
  __builtin_amdgcn_global_load_lds(
      (const __attribute__((address_space(1))) void*)g,
      (__attribute__((address_space(3))) void*)l, 16, 0, 0);
}

// Prep: CHUNK-MAJOR images (proven round-5 structure, re-indexed to 128-row
// tiles). Per (tile, it) the image holds 16B chunks at p = c*128 + r
// (c = k-chunk 0..7, r = row 0..127). The GEMM stages position p to LDS
// chunk p (linear copy), so fragment reads (fixed chunk, 32 consecutive
// rows) are 512B contiguous per half-wave -> conflict-free.
// Read pattern: 8 lanes = 8 chunks of one row (256B contiguous per octet).
// grid (168, 128): x<84 -> A (it = x>>2, i = x&3, mtile = y, rows 0..127);
//                  x>=84 -> B (same shape, ntile = y, only y<64 active).
__global__ __launch_bounds__(256) void prep_kernel(
    const float* __restrict__ conv, const float* __restrict__ Wy,
    const float* __restrict__ Wx, _Float16* __restrict__ A,
    _Float16* __restrict__ B) {
  const int t = threadIdx.x;
  const int bx = blockIdx.x;
  const int c = t & 7;  // chunk index within the BK=64 row
  half8 h;
  if (bx < 84) {  // A part: conv -> f16
    const int tile = blockIdx.y;                     // mtile 0..127
    const int it = bx >> 2, i = bx & 3;
    const int r = (t >> 3) + 32 * i;                 // row in tile, 0..127
    const int k0 = it * 64 + c * 8;
    const int grow = tile * BM + r;
    if (k0 < KRAW) {  // chunk fully valid (KRAW multiple of 8)
      const float* s = conv + (size_t)grow * KRAW + k0;
#pragma unroll
      for (int e = 0; e < 8; e++) h[e] = (_Float16)s[e];
    } else {
#pragma unroll
      for (int e = 0; e < 8; e++) h[e] = (_Float16)0.f;
    }
    *(half8*)(A + (size_t)tile * TILE_H + (size_t)it * IT_H +
              ((size_t)c * 128 + r) * 8) = h;
  } else {  // B part: Wy*Wx*256 -> f16
    const int tile = blockIdx.y;                     // ntile
    if (tile >= 64) return;
    const int bxp = bx - 84;
    const int it = bxp >> 2, i = bxp & 3;
    const int r = (t >> 3) + 32 * i;                 // row in tile, 0..127
    const int k0 = it * 64 + c * 8;
    const int n = tile * BN + r;
    if (k0 < KRAW) {
      const float* wyn = Wy + n * LYC;
      const float* wxn = Wx + n * LXC;
      int y = k0 / LXC;
      int x = k0 - y * LXC;
#pragma unroll
      for (int e = 0; e < 8; e++) {
        h[e] = (_Float16)(wyn[y] * wxn[x] * 256.f);
        if (++x == LXC) { x = 0; ++y; }
      }
    } else {
#pragma unroll
      for (int e = 0; e < 8; e++) h[e] = (_Float16)0.f;
    }
    *(half8*)(B + (size_t)tile * TILE_H + (size_t)it * IT_H +
              ((size_t)c * 128 + r) * 8) = h;
  }
}

// Fused GEMM: block tile 128x128, BK=64, 4 waves (2x2), wave tile 64x64 =
// [2 mb][2 nb] of 32x32x16 f16 MFMA (acc 4 x f32x16 = 64 AGPR -> ~150
// regs/lane total). LDS 64 KB: A,B DOUBLE-buffered -> 2 blocks/CU, AND a
// full-iteration prefetch distance: stage(t+1) -> vmcnt(8) (waits only
// tile t's loads, issued one whole compute-iteration earlier; never 0 in
// the main loop) -> barrier -> compute(t) -> barrier. Same 2-barrier count
// as the proven round-0 skeleton, but the per-iteration L2-latency drain
// is gone. Epilogue contracts 64 channels with Wc, adds bias, ELU.
__global__ __launch_bounds__(256, 2) void gemm_fused_kernel(
    const _Float16* __restrict__ A, const _Float16* __restrict__ B,
    const float* __restrict__ Wc, const float* __restrict__ bias,
    float* __restrict__ out) {
  __shared__ _Float16 As[2][BM * BK];  // 2 x 16 KB, chunk-major c*1024+r*8
  __shared__ _Float16 Bs[2][BN * BK];  // 2 x 16 KB

  // XCD swizzle: xcd = bid&7 owns 8 ntiles x 128 mtiles; ntile varies
  // fastest so the 8 blocks sharing one A-(tile,it) slice run together and
  // the B slice (8 ntiles, 2.75 MB) stays L2-resident per XCD.
  const int bid = blockIdx.x;                 // 0..8191
  const int l = bid >> 3;                     // 0..1023
  const int ntile = (bid & 7) * 8 + (l & 7);  // 0..63
  const int mtile = l >> 3;                   // 0..127
  const int tileN = ntile * BN;

  const int t = threadIdx.x;
  const int lane = t & 63;
  const int wave = t >> 6;
  const int wm = wave >> 1, wn = wave & 1;  // 2x2 waves; wave tile 64x64
  const int r32 = lane & 31, hh = lane >> 5;

  f32x16 acc[2][2] = {};  // [mb][nb], mb: 2x32 rows, nb: 2x32 cols

  const _Float16* pA = A + (size_t)mtile * TILE_H + t * 8;
  const _Float16* pB = B + (size_t)ntile * TILE_H + t * 8;

  auto stage = [&](int b, int it) {
    const _Float16* sA = pA + (size_t)it * IT_H;
    const _Float16* sB = pB + (size_t)it * IT_H;
    _Float16* lA = &As[b][t * 8];
    _Float16* lB = &Bs[b][t * 8];
#pragma unroll
    for (int i = 0; i < 4; i++) async_copy16(sA + i * 2048, lA + i * 2048);
#pragma unroll
    for (int i = 0; i < 4; i++) async_copy16(sB + i * 2048, lB + i * 2048);
  };

  stage(0, 0);
#pragma unroll 1
  for (int it = 0; it < KITER; ++it) {
    const int cbuf = it & 1;
    if (it + 1 < KITER) {
      // buf[cbuf^1]'s readers finished at iteration (it-1)'s trailing
      // barrier, so staging into it here is race-free.
      stage(cbuf ^ 1, it + 1);
      // Outstanding: tile it's 8 + tile (it+1)'s 8. vmcnt(8) retires
      // tile it's loads (issued a full compute-iteration ago -> ~no stall).
      asm volatile("s_waitcnt vmcnt(8)" ::: "memory");
    } else {
      asm volatile("s_waitcnt vmcnt(0)" ::: "memory");
    }
    __builtin_amdgcn_s_barrier();  // buf[cbuf] visible to all waves
#pragma unroll
    for (int ks = 0; ks < 4; ks++) {
      const int cc = 2 * ks + hh;  // source chunk for this k-substep
      half8 bf[2], af[2];
#pragma unroll
      for (int nb = 0; nb < 2; nb++) {
        const int r = wn * 64 + nb * 32 + r32;
        bf[nb] = *(const half8*)(&Bs[cbuf][cc * 1024 + r * 8]);
      }
#pragma unroll
      for (int mb = 0; mb < 2; mb++) {
        const int r = wm * 64 + mb * 32 + r32;
        af[mb] = *(const half8*)(&As[cbuf][cc * 1024 + r * 8]);
      }
#pragma unroll
      for (int mb = 0; mb < 2; mb++)
#pragma unroll
        for (int nb = 0; nb < 2; nb++)
          acc[mb][nb] = __builtin_amdgcn_mfma_f32_32x32x16_f16(
              af[mb], bf[nb], acc[mb][nb], 0, 0, 0);
    }
    __builtin_amdgcn_s_barrier();  // all reads of buf[cbuf] done
  }

  // Epilogue. C/D layout (32x32): col = lane&31 (N), row = (reg&3)+8*(reg>>2)
  // +4*hh (M). Wave M-span = 64 rows = 1 image x 64 channels:
  // img = mtile*2 + wm, channel = mb*32 + (q + 8g + 4hh), reg = g*4+q.
  const int img = mtile * 2 + wm;
#pragma unroll
  for (int nb = 0; nb < 2; nb++) {
    const int n_g = tileN + wn * 64 + nb * 32 + r32;
    const float* wc = Wc + (size_t)n_g * NCONV;
    float p = 0.f;
#pragma unroll
    for (int mb = 0; mb < 2; mb++)
#pragma unroll
      for (int g = 0; g < 4; g++) {
        const f32x4 w = *(const f32x4*)(wc + mb * 32 + hh * 4 + g * 8);
#pragma unroll
        for (int q = 0; q < 4; q++)
          p += acc[mb][nb][g * 4 + q] * w[q];
      }
    p += __shfl_xor(p, 32);  // combine the two hh channel-halves
    if (hh == 0) {
      float z = p * 0.00390625f + bias[n_g];  // undo x256 scaling
      z = z > 0.f ? z : (__expf(z) - 1.f);
      out[(size_t)img * NNEUR + n_g] = z;
    }
  }
}

extern "C" void kernel_launch(void* const* d_in, const int* in_sizes, int n_in,
                              void* d_out, int out_size, void* d_ws,
                              size_t ws_size, hipStream_t stream) {
  const float* conv = (const float*)d_in[0];
  const float* Wc = (const float*)d_in[1];
  const float* Wy = (const float*)d_in[2];
  const float* Wx = (const float*)d_in[3];
  const float* bias = (const float*)d_in[4];
  float* out = (float*)d_out;

  _Float16* Abuf = (_Float16*)d_ws;                                      // 44.0 MB
  _Float16* Bbuf = (_Float16*)((char*)d_ws + (size_t)MROWS * KPAD * 2);  // 22.0 MB

  prep_kernel<<<dim3(168, 128), 256, 0, stream>>>(conv, Wy, Wx, Abuf, Bbuf);
  gemm_fused_kernel<<<8192, 256, 0, stream>>>(Abuf, Bbuf, Wc, bias, out);
}

// Round 7
// 491.358 us; speedup vs baseline: 1.1299x; 1.1299x over previous
//
#include <hip/hip_runtime.h>
#include <hip/hip_bf16.h>

// Problem constants
#define NNEUR 8192
#define NCONV 64
#define LYC   36
#define LXC   36
#define BATCH 256
#define KRAW  1296   // 36*36
#define KPAD  1344   // 21*64
#define KITER 21     // KPAD/64
#define MROWS 16384  // BATCH*NCONV
#define BM 256
#define BN 128
#define BK 64
// Staged-chunk geometry: one chunk = 16 B = 8 halfs.
#define ACH_PER_IT 2048   // BM*BK/8
#define BCH_PER_IT 1024   // BN*BK/8
#define A_TILE_H   (KITER * ACH_PER_IT * 8)  // halfs per m-tile = 344064
#define B_TILE_H   (KITER * BCH_PER_IT * 8)  // halfs per n-tile = 172032

typedef __attribute__((ext_vector_type(8))) _Float16 half8;
typedef __attribute__((ext_vector_type(4))) float f32x4;
typedef __attribute__((ext_vector_type(16))) float f32x16;

__device__ __forceinline__ void async_copy16(const void* g, void* l) {
  __builtin_amdgcn_global_load_lds(
      (const __attribute__((address_space(1))) void*)g,
      (__attribute__((address_space(3))) void*)l, 16, 0, 0);
}

// Prep v5: LDS-transpose prep emitting the ROUND-0 image (byte-identical):
// per (tile, it), 16B-slot p = r*8 + s holds source chunk c = (s - r)&7 of
// row r. Produce side reads conv fully coalesced (8 lanes = 8 chunks =
// 256B of one row) and ds_writes slot r*8 + (c ^ (r&7)) -- per-wave 1KB
// contiguous, conflict-free. Consume side walks output slots linearly
// (q = t + 256j): r = q>>3 advances per octet, so LDS reads are also 1KB
// contiguous permuted (conflict-free) and global stores are 4KB contiguous
// per wave-iteration. Grid (KITER, 64): one block per (it, tile); A image
// (mtile = tile, 32KB) then B image (ntile = tile, 16KB) reusing the LDS.
__global__ __launch_bounds__(256) void prep_kernel(
    const float* __restrict__ conv, const float* __restrict__ Wy,
    const float* __restrict__ Wx, _Float16* __restrict__ A,
    _Float16* __restrict__ B) {
  __shared__ _Float16 lds[2048 * 8];  // 32 KB = 2048 16B slots
  half8* slots = (half8*)lds;
  const int t = threadIdx.x;
  const int it = blockIdx.x;    // 0..20
  const int tile = blockIdx.y;  // 0..63
  const int c = t & 7;          // produce-side chunk
  const int rb = t >> 3;        // 0..31
  const int k0 = it * 64 + c * 8;
  const bool kv = (k0 < KRAW);  // KRAW % 8 == 0 -> chunk all-valid or none

  // ---- A produce: conv -> f16 -> LDS (transposed) ----
  const float* convb = conv + (size_t)tile * BM * KRAW;
#pragma unroll
  for (int j = 0; j < 8; ++j) {
    const int r = rb + 32 * j;  // 0..255
    half8 h;
    if (kv) {
      // (row*KRAW + k0)*4B is 32B-aligned: 1296*4 % 32 == 0, k0*4 % 32 == 0
      const f32x4* sp = (const f32x4*)(convb + (size_t)r * KRAW + k0);
      const f32x4 lo = sp[0], hi = sp[1];
#pragma unroll
      for (int e = 0; e < 4; e++) {
        h[e] = (_Float16)lo[e];
        h[e + 4] = (_Float16)hi[e];
      }
    } else {
#pragma unroll
      for (int e = 0; e < 8; e++) h[e] = (_Float16)0.f;
    }
    slots[r * 8 + (c ^ (r & 7))] = h;
  }
  __syncthreads();
  // ---- A consume: LDS -> global, 4KB contiguous per wave-iter ----
  _Float16* Ab = A + (size_t)tile * A_TILE_H + (size_t)it * (ACH_PER_IT * 8);
#pragma unroll
  for (int j = 0; j < 8; ++j) {
    const int q = t + 256 * j;  // output slot
    const int r = q >> 3, s = q & 7;
    const int cq = (s - r) & 7;
    *(half8*)(Ab + (size_t)q * 8) = slots[r * 8 + (cq ^ (r & 7))];
  }
  __syncthreads();

  // ---- B produce: Wy*Wx*256 -> f16 -> LDS (rows 0..127) ----
#pragma unroll
  for (int j = 0; j < 4; ++j) {
    const int r = rb + 32 * j;  // 0..127
    const int n = tile * BN + r;
    half8 h;
    if (kv) {
      const float* wyn = Wy + n * LYC;
      const float* wxn = Wx + n * LXC;
      int y = k0 / LXC;
      int x = k0 - y * LXC;
#pragma unroll
      for (int e = 0; e < 8; e++) {
        h[e] = (_Float16)(wyn[y] * wxn[x] * 256.f);
        if (++x == LXC) { x = 0; ++y; }
      }
    } else {
#pragma unroll
      for (int e = 0; e < 8; e++) h[e] = (_Float16)0.f;
    }
    slots[r * 8 + (c ^ (r & 7))] = h;
  }
  __syncthreads();
  // ---- B consume ----
  _Float16* Bb = B + (size_t)tile * B_TILE_H + (size_t)it * (BCH_PER_IT * 8);
#pragma unroll
  for (int j = 0; j < 4; ++j) {
    const int q = t + 256 * j;  // 0..1023
    const int r = q >> 3, s = q & 7;
    const int cq = (s - r) & 7;
    *(half8*)(Bb + (size_t)q * 8) = slots[r * 8 + (cq ^ (r & 7))];
  }
}

// Fused GEMM: block tile 256(M)x128(N), BK=64, 4 waves each 128x64 using
// 32x32x16 f16 MFMA (acc 8 x f32x16 = 128 AGPR). Epilogue contracts the 64
// channels with Wc, adds bias, ELU. LDS 48 KB single-buffered.
// BYTE-IDENTICAL to the round-0 kernel (357-371 us across sessions,
// MfmaUtil ~47%): the 2-barrier single-buffer schedule with ~3 blocks/CU
// inter-block overlap beat counted-vmcnt 256^2, per-phase-barrier 256^2,
// B-direct-to-reg, and 128^2 double-buffer (rounds 1-3, 6). GEMM structure
// converged; this round only changes prep.
__global__ __launch_bounds__(256, 3) void gemm_fused_kernel(
    const _Float16* __restrict__ A, const _Float16* __restrict__ B,
    const float* __restrict__ Wc, const float* __restrict__ bias,
    float* __restrict__ out) {
  __shared__ _Float16 As[BM * BK];  // 32 KB
  __shared__ _Float16 Bs[BN * BK];  // 16 KB

  // XCD swizzle: xcd = bid&7; within an XCD, n varies fastest so the 8
  // blocks sharing one A-tile are consecutive; B panel (8 n-tiles, 2.75 MB)
  // stays L2-resident per XCD.
  const int bid = blockIdx.x;      // 0..4095
  const int l = bid >> 3;          // 0..511
  const int ntile = (bid & 7) * 8 + (l & 7);  // 0..63
  const int mtile = l >> 3;                   // 0..63
  const int tileN = ntile * BN;

  const int t = threadIdx.x;
  const int lane = t & 63;
  const int wave = t >> 6;
  const int wm = wave >> 1, wn = wave & 1;  // 2x2 waves; wave tile 128x64
  const int r32 = lane & 31, hh = lane >> 5;

  f32x16 acc[4][2] = {};  // [mb][nb], mb: 4x32 rows, nb: 2x32 cols

  const _Float16* pA = A + (size_t)mtile * A_TILE_H;
  const _Float16* pB = B + (size_t)ntile * B_TILE_H;
  _Float16* lA = As + t * 8;
  _Float16* lB = Bs + t * 8;

  for (int it = 0; it < KITER; it++) {
    const _Float16* sA = pA + (size_t)it * (ACH_PER_IT * 8) + t * 8;
    const _Float16* sB = pB + (size_t)it * (BCH_PER_IT * 8) + t * 8;
#pragma unroll
    for (int i = 0; i < 8; i++) async_copy16(sA + i * 2048, lA + i * 2048);
#pragma unroll
    for (int i = 0; i < 4; i++) async_copy16(sB + i * 2048, lB + i * 2048);
    __syncthreads();

#pragma unroll
    for (int ks = 0; ks < 4; ks++) {
      const int cc = 2 * ks + hh;  // source chunk for this k-substep
      half8 bf[2];
#pragma unroll
      for (int nb = 0; nb < 2; nb++) {
        const int r = wn * 64 + nb * 32 + r32;
        bf[nb] = *(const half8*)(Bs + r * 64 + ((cc + r) & 7) * 8);
      }
#pragma unroll
      for (int mb = 0; mb < 4; mb++) {
        const int r = wm * 128 + mb * 32 + r32;
        const half8 af = *(const half8*)(As + r * 64 + ((cc + r) & 7) * 8);
#pragma unroll
        for (int nb = 0; nb < 2; nb++)
          acc[mb][nb] = __builtin_amdgcn_mfma_f32_32x32x16_f16(
              af, bf[nb], acc[mb][nb], 0, 0, 0);
      }
    }
    __syncthreads();
  }

  // Epilogue. C/D layout (32x32): col = lane&31, row = (reg&3)+8*(reg>>2)+4*hh.
  // Wave rows = 128 = 2 images x 64 channels; mb pairs (0,1)->img0, (2,3)->img1;
  // channel = (mb&1)*32 + row.
  const int ibase = mtile * 4 + wm * 2;
  float v[2][2];  // [img][nb]
#pragma unroll
  for (int nb = 0; nb < 2; nb++) {
    const int n_g = tileN + wn * 64 + nb * 32 + r32;
    const float* wc = Wc + (size_t)n_g * NCONV;
    f32x4 w[2][4];
#pragma unroll
    for (int hf = 0; hf < 2; hf++)
#pragma unroll
      for (int g = 0; g < 4; g++)
        w[hf][g] = *(const f32x4*)(wc + hf * 32 + hh * 4 + g * 8);
#pragma unroll
    for (int img = 0; img < 2; img++) {
      float p = 0.f;
#pragma unroll
      for (int hf = 0; hf < 2; hf++)
#pragma unroll
        for (int g = 0; g < 4; g++)
#pragma unroll
          for (int q = 0; q < 4; q++)
            p += acc[img * 2 + hf][nb][g * 4 + q] * w[hf][g][q];
      p += __shfl_xor(p, 32);
      v[img][nb] = p;
    }
  }
  // Each lane writes image hh (its half), both nb; values identical per half.
  const int img = ibase + hh;
#pragma unroll
  for (int nb = 0; nb < 2; nb++) {
    const int n_out = tileN + wn * 64 + nb * 32 + r32;
    float z = v[hh][nb] * 0.00390625f + bias[n_out];  // undo x256 scaling
    z = z > 0.f ? z : (__expf(z) - 1.f);
    out[(size_t)img * NNEUR + n_out] = z;
  }
}

extern "C" void kernel_launch(void* const* d_in, const int* in_sizes, int n_in,
                              void* d_out, int out_size, void* d_ws,
                              size_t ws_size, hipStream_t stream) {
  const float* conv = (const float*)d_in[0];
  const float* Wc = (const float*)d_in[1];
  const float* Wy = (const float*)d_in[2];
  const float* Wx = (const float*)d_in[3];
  const float* bias = (const float*)d_in[4];
  float* out = (float*)d_out;

  _Float16* Abuf = (_Float16*)d_ws;                                      // 44.0 MB
  _Float16* Bbuf = (_Float16*)((char*)d_ws + (size_t)MROWS * KPAD * 2);  // 22.0 MB

  prep_kernel<<<dim3(KITER, 64), 256, 0, stream>>>(conv, Wy, Wx, Abuf, Bbuf);
  gemm_fused_kernel<<<4096, 256, 0, stream>>>(Abuf, Bbuf, Wc, bias, out);
}